// Round 2
// baseline (948.571 us; speedup 1.0000x reference)
//
#include <hip/hip_runtime.h>
#include <hip/hip_bf16.h>

// WindowCrossAttention fused kernel for MI355X (gfx950).
// B=4096 windows, N=49 tokens, C=256, H=8 heads, d=32.
// One block per window; 8 waves; all intermediates in LDS; bf16 MFMA 16x16x32.
//
// R1 changes vs R0 (never benched - broker timeout):
//  - RACE FIX: per-wave attn tiles (sa) overlap the Q region for waves 4-7.
//    Added __syncthreads() between Q-fragment reads and sa stores, and between
//    sa reads (PV) and attn-out stores into LDS_Q.
//  - ws shrunk 5.4MB -> 601KB (gathered per-head bias only; mask added from
//    global per block, L2-resident).

typedef __attribute__((ext_vector_type(8))) short bf16x8;   // 8 bf16 = 4 VGPR
typedef __attribute__((ext_vector_type(4))) float f32x4;

#define NTOK 49
#define CCH  256

// LDS layout (bytes). Rows padded to 64 for 4 M-tiles of 16.
#define LDS_XY  0        // [64][256] bf16 swizzled (x, then y, then per-wave attn tiles 8x8KB spanning XY+Q)
#define LDS_Q   32768    // [64][256] bf16 (q, later attention output)
#define LDS_K   65536    // [64][256] bf16
#define LDS_VT  98304    // [256][64] bf16 (v transposed: [dd][token])
#define LDS_RED 131072   // [64 rows][8 waves][2] f32 partial sums
#define LDS_MU  135168   // [64 rows][2] f32 (mu, rsigma)
#define LDS_TOT 135680

__device__ __forceinline__ unsigned short f2bf(float f) {
  // round-to-nearest-even fp32 -> bf16
  unsigned u = __float_as_uint(f);
  unsigned r = (u + 0x7FFFu + ((u >> 16) & 1u)) >> 16;
  return (unsigned short)r;
}

// XOR swizzle: row-major tiles with 512B/128B rows otherwise hit 16/32-way
// LDS bank conflicts on ds_read_b128 (T2, guide §6 G4).
__device__ __forceinline__ int swz512(int r, int cbyte) { return r * 512 + (cbyte ^ ((r & 7) << 4)); }
__device__ __forceinline__ int swz128(int r, int cbyte) { return r * 128 + (cbyte ^ ((r & 7) << 4)); }

// 64x32 tile of  out = A[64][256] @ W^T  ; W row-major [co][ci] feeds the
// B-fragment directly (col = lane&15 -> co row, k = (lane>>4)*8+e contiguous).
__device__ __forceinline__ void gemm256(const char* sm, int base_a,
                                        const unsigned short* __restrict__ W,
                                        int w, int r16, int g, f32x4 acc[4][2]) {
#pragma unroll
  for (int k0 = 0; k0 < 8; ++k0) {
    const int kk = k0 * 32 + g * 8;
    bf16x8 a[4], bb[2];
#pragma unroll
    for (int mt = 0; mt < 4; ++mt)
      a[mt] = *(const bf16x8*)(sm + base_a + swz512(mt * 16 + r16, kk * 2));
#pragma unroll
    for (int nt = 0; nt < 2; ++nt)
      bb[nt] = *(const bf16x8*)(W + (w * 32 + nt * 16 + r16) * CCH + kk);
#pragma unroll
    for (int mt = 0; mt < 4; ++mt)
#pragma unroll
      for (int nt = 0; nt < 2; ++nt)
        acc[mt][nt] = __builtin_amdgcn_mfma_f32_16x16x32_bf16(a[mt], bb[nt], acc[mt][nt], 0, 0, 0);
  }
}

__device__ __forceinline__ void stage49(char* sm, const float* __restrict__ src, int tid) {
  // [49][256] fp32 -> LDS bf16 swizzled, rows 49..63 assumed already zero
#pragma unroll 2
  for (int idx = tid; idx < (NTOK * CCH) / 4; idx += 512) {
    int r = idx >> 6;
    int c = (idx & 63) << 2;
    float4 v = *(const float4*)(src + r * CCH + c);
    uint2 pk;
    pk.x = (unsigned)f2bf(v.x) | ((unsigned)f2bf(v.y) << 16);
    pk.y = (unsigned)f2bf(v.z) | ((unsigned)f2bf(v.w) << 16);
    *(uint2*)(sm + LDS_XY + swz512(r, c * 2)) = pk;
  }
}

// ---------------- prep kernels ----------------

__global__ void prep_weights(const float* __restrict__ wq, const float* __restrict__ wk,
                             const float* __restrict__ wv, const float* __restrict__ pw,
                             unsigned short* __restrict__ o) {
  int i = blockIdx.x * 256 + threadIdx.x;   // 65536 threads
  o[i]            = f2bf(wq[i]);
  o[65536 + i]    = f2bf(wk[i]);
  o[131072 + i]   = f2bf(wv[i]);
  o[196608 + i]   = f2bf(pw[i]);
}

__global__ void prep_bias(const float* __restrict__ btab, const int* __restrict__ rpi,
                          float* __restrict__ bt) {
  int h = blockIdx.x;   // 8 heads
  for (int i = threadIdx.x; i < NTOK * NTOK; i += 256)
    bt[h * NTOK * NTOK + i] = btab[rpi[i] * 8 + h];
}

// ---------------- main fused kernel ----------------

__global__ __launch_bounds__(512, 2) void wca_main(
    const float* __restrict__ x, const float* __restrict__ y,
    const unsigned short* __restrict__ wbf,   // wq|wk|wv|proj, each 256*256 bf16
    const float* __restrict__ wq_b, const float* __restrict__ wk_b,
    const float* __restrict__ wv_b, const float* __restrict__ proj_b,
    const float* __restrict__ bt,             // [8][49][49] gathered rel-pos bias
    const float* __restrict__ mask,           // [64][49][49] shift mask
    const float* __restrict__ ln_g, const float* __restrict__ ln_b,
    float* __restrict__ out) {
  __shared__ __align__(16) char sm[LDS_TOT];
  const int tid = threadIdx.x;
  const int lane = tid & 63;
  const int w = tid >> 6;           // wave = head = 32-col slice
  const int r16 = lane & 15;
  const int g = lane >> 4;
  const int b = blockIdx.x;
  const size_t bbase = (size_t)b * NTOK * CCH;
  const float* xb = x + bbase;
  const float* yb = y + bbase;

  // zero pad rows 49..63 of the staging tile (stays zero through y restage)
  for (int idx = tid; idx < 15 * 64; idx += 512) {
    int r = 49 + (idx >> 6);
    int c = (idx & 63) << 2;
    *(uint2*)(sm + LDS_XY + swz512(r, c * 2)) = make_uint2(0u, 0u);
  }
  stage49(sm, xb, tid);
  __syncthreads();

  // ---- Q = x @ Wq^T + bq ----
  {
    f32x4 acc[4][2];
#pragma unroll
    for (int i = 0; i < 4; ++i) { acc[i][0] = (f32x4)(0.0f); acc[i][1] = (f32x4)(0.0f); }
    gemm256(sm, LDS_XY, wbf, w, r16, g, acc);
#pragma unroll
    for (int nt = 0; nt < 2; ++nt) {
      int col = w * 32 + nt * 16 + r16;
      float bv = wq_b[col];
#pragma unroll
      for (int mt = 0; mt < 4; ++mt)
#pragma unroll
        for (int r = 0; r < 4; ++r) {
          int row = mt * 16 + g * 4 + r;   // D-layout: row=(lane>>4)*4+reg
          *(unsigned short*)(sm + LDS_Q + swz512(row, col * 2)) = f2bf(acc[mt][nt][r] + bv);
        }
    }
  }
  __syncthreads();

  stage49(sm, yb, tid);   // y over x
  __syncthreads();

  // ---- K = y @ Wk^T + bk ----
  {
    f32x4 acc[4][2];
#pragma unroll
    for (int i = 0; i < 4; ++i) { acc[i][0] = (f32x4)(0.0f); acc[i][1] = (f32x4)(0.0f); }
    gemm256(sm, LDS_XY, wbf + 65536, w, r16, g, acc);
#pragma unroll
    for (int nt = 0; nt < 2; ++nt) {
      int col = w * 32 + nt * 16 + r16;
      float bv = wk_b[col];
#pragma unroll
      for (int mt = 0; mt < 4; ++mt)
#pragma unroll
        for (int r = 0; r < 4; ++r) {
          int row = mt * 16 + g * 4 + r;
          *(unsigned short*)(sm + LDS_K + swz512(row, col * 2)) = f2bf(acc[mt][nt][r] + bv);
        }
    }
  }
  // ---- V = y @ Wv^T + bv, stored transposed [dd][token] ----
  {
    f32x4 acc[4][2];
#pragma unroll
    for (int i = 0; i < 4; ++i) { acc[i][0] = (f32x4)(0.0f); acc[i][1] = (f32x4)(0.0f); }
    gemm256(sm, LDS_XY, wbf + 131072, w, r16, g, acc);
#pragma unroll
    for (int nt = 0; nt < 2; ++nt) {
      int col = w * 32 + nt * 16 + r16;   // dd (global channel)
      float bv = wv_b[col];
#pragma unroll
      for (int mt = 0; mt < 4; ++mt)
#pragma unroll
        for (int r = 0; r < 4; ++r) {
          int row = mt * 16 + g * 4 + r;  // token
          *(unsigned short*)(sm + LDS_VT + swz128(col, row * 2)) = f2bf(acc[mt][nt][r] + bv);
        }
    }
  }
  __syncthreads();   // protects sXY (y dead after this) + sK/sVT visibility

  // ---- attention: wave w == head w; reads only its own q/k/vT column slices ----
  float rs[4][4];
  char* sa = sm + LDS_XY + w * 8192;      // per-wave [64][64] bf16 attn tile (spans XY+Q regions!)
  f32x4 s[4][4];
  {
#pragma unroll
    for (int i = 0; i < 4; ++i)
#pragma unroll
      for (int j = 0; j < 4; ++j) s[i][j] = (f32x4)(0.0f);
    const int kk = w * 32 + g * 8;        // head's 32-dim slice
    bf16x8 qf[4], kf[4];
#pragma unroll
    for (int mt = 0; mt < 4; ++mt) qf[mt] = *(const bf16x8*)(sm + LDS_Q + swz512(mt * 16 + r16, kk * 2));
#pragma unroll
    for (int nt = 0; nt < 4; ++nt) kf[nt] = *(const bf16x8*)(sm + LDS_K + swz512(nt * 16 + r16, kk * 2));
#pragma unroll
    for (int mt = 0; mt < 4; ++mt)
#pragma unroll
      for (int nt = 0; nt < 4; ++nt)
        s[mt][nt] = __builtin_amdgcn_mfma_f32_16x16x32_bf16(qf[mt], kf[nt], s[mt][nt], 0, 0, 0);

    const float scale = 0.17677669529663687f;   // 1/sqrt(32)
    const float* bp = bt + w * (NTOK * NTOK);
    const float* mp = mask + (size_t)(b & 63) * (NTOK * NTOK);
#pragma unroll
    for (int mt = 0; mt < 4; ++mt)
#pragma unroll
      for (int nt = 0; nt < 4; ++nt) {
        int col = nt * 16 + r16;
#pragma unroll
        for (int r = 0; r < 4; ++r) {
          int row = mt * 16 + g * 4 + r;
          float v = s[mt][nt][r] * scale;
          if (col < NTOK) { if (row < NTOK) v += bp[row * NTOK + col] + mp[row * NTOK + col]; }
          else v = -1e30f;                 // mask padded keys
          s[mt][nt][r] = v;
        }
      }
    // wave-parallel softmax per row (row lives in one 16-lane group, 4 cols/lane)
#pragma unroll
    for (int mt = 0; mt < 4; ++mt)
#pragma unroll
      for (int r = 0; r < 4; ++r) {
        float m = fmaxf(fmaxf(s[mt][0][r], s[mt][1][r]), fmaxf(s[mt][2][r], s[mt][3][r]));
        m = fmaxf(m, __shfl_xor(m, 1)); m = fmaxf(m, __shfl_xor(m, 2));
        m = fmaxf(m, __shfl_xor(m, 4)); m = fmaxf(m, __shfl_xor(m, 8));
        float sum = 0.f;
#pragma unroll
        for (int nt = 0; nt < 4; ++nt) {
          float e = __expf(s[mt][nt][r] - m);
          s[mt][nt][r] = e;
          sum += e;
        }
        sum += __shfl_xor(sum, 1); sum += __shfl_xor(sum, 2);
        sum += __shfl_xor(sum, 4); sum += __shfl_xor(sum, 8);
        rs[mt][r] = 1.0f / sum;            // defer normalization to after PV
      }
  }
  // RACE FIX: all waves must finish reading Q (qf) before sa stores land on the
  // Q region (waves 4-7 park their sa tiles there).
  __syncthreads();
#pragma unroll
  for (int mt = 0; mt < 4; ++mt)
#pragma unroll
    for (int r = 0; r < 4; ++r) {
      int row = mt * 16 + g * 4 + r;
#pragma unroll
      for (int nt = 0; nt < 4; ++nt) {
        int col = nt * 16 + r16;
        *(unsigned short*)(sa + swz128(row, col * 2)) = f2bf(s[mt][nt][r]);
      }
    }
  __syncthreads();   // sa tiles complete (also orders vs. own reads below)

  // ---- PV: out_h = attn @ v_h ----
  {
    f32x4 o[4][2];
#pragma unroll
    for (int i = 0; i < 4; ++i) { o[i][0] = (f32x4)(0.0f); o[i][1] = (f32x4)(0.0f); }
#pragma unroll
    for (int kk2 = 0; kk2 < 2; ++kk2) {
      const int key = kk2 * 32 + g * 8;
      bf16x8 pa[4], vb[2];
#pragma unroll
      for (int mt = 0; mt < 4; ++mt) pa[mt] = *(const bf16x8*)(sa + swz128(mt * 16 + r16, key * 2));
#pragma unroll
      for (int nt = 0; nt < 2; ++nt)
        vb[nt] = *(const bf16x8*)(sm + LDS_VT + swz128(w * 32 + nt * 16 + r16, key * 2));
#pragma unroll
      for (int mt = 0; mt < 4; ++mt)
#pragma unroll
        for (int nt = 0; nt < 2; ++nt)
          o[mt][nt] = __builtin_amdgcn_mfma_f32_16x16x32_bf16(pa[mt], vb[nt], o[mt][nt], 0, 0, 0);
    }
    // RACE FIX: all waves must finish reading their sa tiles before attn-out
    // stores land on LDS_Q (which overlaps waves 4-7's sa tiles).
    __syncthreads();
    // normalize rows, write attn-out into sQ region (own cols only -> race-free)
#pragma unroll
    for (int nt = 0; nt < 2; ++nt) {
      int col = w * 32 + nt * 16 + r16;
#pragma unroll
      for (int mt = 0; mt < 4; ++mt)
#pragma unroll
        for (int r = 0; r < 4; ++r) {
          int row = mt * 16 + g * 4 + r;
          *(unsigned short*)(sm + LDS_Q + swz512(row, col * 2)) = f2bf(o[mt][nt][r] * rs[mt][r]);
        }
    }
  }
  __syncthreads();   // all heads' outputs in sQ

  // ---- proj + residual + LayerNorm ----
  {
    f32x4 acc[4][2];
#pragma unroll
    for (int i = 0; i < 4; ++i) { acc[i][0] = (f32x4)(0.0f); acc[i][1] = (f32x4)(0.0f); }
    gemm256(sm, LDS_Q, wbf + 196608, w, r16, g, acc);
    float h[4][2][4];
#pragma unroll
    for (int nt = 0; nt < 2; ++nt) {
      int col = w * 32 + nt * 16 + r16;
      float pb = proj_b[col];
#pragma unroll
      for (int mt = 0; mt < 4; ++mt)
#pragma unroll
        for (int r = 0; r < 4; ++r) {
          int row = mt * 16 + g * 4 + r;
          float xv = (row < NTOK) ? xb[row * CCH + col] : 0.0f;
          h[mt][nt][r] = acc[mt][nt][r] + pb + xv;
        }
    }
    float* red = (float*)(sm + LDS_RED);
#pragma unroll
    for (int mt = 0; mt < 4; ++mt)
#pragma unroll
      for (int r = 0; r < 4; ++r) {
        float a0 = h[mt][0][r], a1 = h[mt][1][r];
        float s1 = a0 + a1;
        float s2 = a0 * a0 + a1 * a1;
        s1 += __shfl_xor(s1, 1); s2 += __shfl_xor(s2, 1);
        s1 += __shfl_xor(s1, 2); s2 += __shfl_xor(s2, 2);
        s1 += __shfl_xor(s1, 4); s2 += __shfl_xor(s2, 4);
        s1 += __shfl_xor(s1, 8); s2 += __shfl_xor(s2, 8);
        if (r16 == 0) {
          int row = mt * 16 + g * 4 + r;
          red[(row * 8 + w) * 2 + 0] = s1;
          red[(row * 8 + w) * 2 + 1] = s2;
        }
      }
    __syncthreads();
    float* mus = (float*)(sm + LDS_MU);
    if (tid < 64) {
      float s1 = 0.f, s2 = 0.f;
#pragma unroll
      for (int ww = 0; ww < 8; ++ww) { s1 += red[(tid * 8 + ww) * 2]; s2 += red[(tid * 8 + ww) * 2 + 1]; }
      float mu = s1 * (1.0f / 256.0f);
      float var = s2 * (1.0f / 256.0f) - mu * mu;
      mus[tid * 2] = mu;
      mus[tid * 2 + 1] = rsqrtf(var + 1e-5f);
    }
    __syncthreads();
    float* op = out + bbase;
#pragma unroll
    for (int nt = 0; nt < 2; ++nt) {
      int col = w * 32 + nt * 16 + r16;
      float gg = ln_g[col], bb2 = ln_b[col];
#pragma unroll
      for (int mt = 0; mt < 4; ++mt)
#pragma unroll
        for (int r = 0; r < 4; ++r) {
          int row = mt * 16 + g * 4 + r;
          if (row < NTOK)
            op[row * CCH + col] = (h[mt][nt][r] - mus[row * 2]) * mus[row * 2 + 1] * gg + bb2;
        }
    }
  }
}

extern "C" void kernel_launch(void* const* d_in, const int* in_sizes, int n_in,
                              void* d_out, int out_size, void* d_ws, size_t ws_size,
                              hipStream_t stream) {
  const float* x      = (const float*)d_in[0];
  const float* y      = (const float*)d_in[1];
  const float* mask   = (const float*)d_in[2];
  const float* wq_w   = (const float*)d_in[3];
  const float* wq_b   = (const float*)d_in[4];
  const float* wk_w   = (const float*)d_in[5];
  const float* wk_b   = (const float*)d_in[6];
  const float* wv_w   = (const float*)d_in[7];
  const float* wv_b   = (const float*)d_in[8];
  const float* btab   = (const float*)d_in[9];
  const float* proj_w = (const float*)d_in[10];
  const float* proj_b = (const float*)d_in[11];
  const float* ln_g   = (const float*)d_in[12];
  const float* ln_b   = (const float*)d_in[13];
  const int*   rpi    = (const int*)d_in[14];

  unsigned short* wbf = (unsigned short*)d_ws;              // 4 * 256*256 bf16 = 512 KB
  float* bt = (float*)((char*)d_ws + 4 * 65536 * 2);        // [8][49][49] f32 = 76.8 KB

  prep_weights<<<256, 256, 0, stream>>>(wq_w, wk_w, wv_w, proj_w, wbf);
  prep_bias<<<8, 256, 0, stream>>>(btab, rpi, bt);
  wca_main<<<4096, 512, 0, stream>>>(x, y, wbf, wq_b, wk_b, wv_b, proj_b, bt, mask,
                                     ln_g, ln_b, (float*)d_out);
}